// Round 4
// baseline (153.881 us; speedup 1.0000x reference)
//
#include <hip/hip_runtime.h>

// ---------------------------------------------------------------------------
// Native Sparse Attention (B=2, H=8, S=2048, D=64)
// Tile = (bh, qb): 64 queries. 512 threads = 8 waves, wave owns 8 queries.
// cmp branch + block selection: exact fp32 (selection-critical).
// sel/win QK: split-bf16 MFMA (QhKh + QhKl + QlKh), logit err ~1e-5.
// sel/win PV: bf16 MFMA (P_bf16 x V_bf16hi), err ~2e-3 << 0.053 budget.
// Staging loops register-prefetch the next block (T14 async-stage split).
// ---------------------------------------------------------------------------

constexpr int SS   = 2048;
constexpr int DD   = 64;
constexpr int NBLK = 32;
constexpr int BS   = 64;
constexpr int SNB  = 8;
constexpr int KKEEP = 256;
constexpr float SCALE  = 0.125f;
constexpr float NEGINF = -1e30f;

#define DEV __device__ __forceinline__

typedef __attribute__((ext_vector_type(8))) short s8_t;   // 8 x bf16 (4 VGPR)
typedef __attribute__((ext_vector_type(4))) float f4_t;   // MFMA C/D frag

union S8U  { uint4 u; s8_t s; };
union S8H  { unsigned short h[8]; s8_t s; };

DEV s8_t as_s8(uint4 u) { S8U x; x.u = u; return x.s; }

DEV float readlane_f(float x, int l) {
  return __int_as_float(__builtin_amdgcn_readlane(__float_as_int(x), l));
}
DEV float wave_max(float x) {
#pragma unroll
  for (int off = 32; off > 0; off >>= 1) x = fmaxf(x, __shfl_xor(x, off, 64));
  return x;
}
DEV float wave_sum(float x) {
#pragma unroll
  for (int off = 32; off > 0; off >>= 1) x += __shfl_xor(x, off, 64);
  return x;
}
DEV unsigned short f2bh(float x) {
  unsigned u = __float_as_uint(x);
  unsigned r = u + 0x7FFFu + ((u >> 16) & 1u);
  return (unsigned short)(r >> 16);
}
DEV float bh2f(unsigned short h) { return __uint_as_float(((unsigned)h) << 16); }

DEV f4_t mfma16(s8_t a, s8_t b, f4_t c) {
  return __builtin_amdgcn_mfma_f32_16x16x32_bf16(a, b, c, 0, 0, 0);
}
DEV void wave_fence() {
  asm volatile("s_waitcnt lgkmcnt(0)" ::: "memory");
  __builtin_amdgcn_sched_barrier(0);
}

// ---- staging register loads (prefetchable) ----
DEV void loadK(const float* __restrict__ src, int tid, float4& a, float4& b) {
  const int r = tid >> 4, c4 = tid & 15;
  a = *(const float4*)(src + r * DD + c4 * 4);
  b = *(const float4*)(src + (r + 32) * DD + c4 * 4);
}
DEV void loadV(const float* __restrict__ src, int tid, float4& a, float4& b) {
  const int tp = tid & 31, dg = tid >> 5;
  a = *(const float4*)(src + (2 * tp) * DD + dg * 4);
  b = *(const float4*)(src + (2 * tp + 1) * DD + dg * 4);
}
// convert + write K block split-bf16: [tok][dim-pairs], row stride 40 uints
DEV void writeK(unsigned int* kh, unsigned int* kl, const float4& a,
                const float4& b, int tid) {
  const int r = tid >> 4, c4 = tid & 15;
  const float fa[4] = {a.x, a.y, a.z, a.w};
  const float fb[4] = {b.x, b.y, b.z, b.w};
  unsigned short h[4], l[4];
#pragma unroll
  for (int i = 0; i < 4; ++i) { h[i] = f2bh(fa[i]); l[i] = f2bh(fa[i] - bh2f(h[i])); }
  kh[r * 40 + c4 * 2]     = (unsigned)h[0] | ((unsigned)h[1] << 16);
  kh[r * 40 + c4 * 2 + 1] = (unsigned)h[2] | ((unsigned)h[3] << 16);
  kl[r * 40 + c4 * 2]     = (unsigned)l[0] | ((unsigned)l[1] << 16);
  kl[r * 40 + c4 * 2 + 1] = (unsigned)l[2] | ((unsigned)l[3] << 16);
#pragma unroll
  for (int i = 0; i < 4; ++i) { h[i] = f2bh(fb[i]); l[i] = f2bh(fb[i] - bh2f(h[i])); }
  kh[(r + 32) * 40 + c4 * 2]     = (unsigned)h[0] | ((unsigned)h[1] << 16);
  kh[(r + 32) * 40 + c4 * 2 + 1] = (unsigned)h[2] | ((unsigned)h[3] << 16);
  kl[(r + 32) * 40 + c4 * 2]     = (unsigned)l[0] | ((unsigned)l[1] << 16);
  kl[(r + 32) * 40 + c4 * 2 + 1] = (unsigned)l[2] | ((unsigned)l[3] << 16);
}
// convert + write V transposed bf16-hi: [dim][tok-pairs], row stride 40 uints
DEV void writeVT(unsigned int* vh, const float4& a, const float4& b, int tid) {
  const int tp = tid & 31, dg = tid >> 5;
  const float fa[4] = {a.x, a.y, a.z, a.w};
  const float fb[4] = {b.x, b.y, b.z, b.w};
#pragma unroll
  for (int i = 0; i < 4; ++i)
    vh[(dg * 4 + i) * 40 + tp] = (unsigned)f2bh(fa[i]) | ((unsigned)f2bh(fb[i]) << 16);
}

// --- QK mfma: C[q][tok], K=64 dims, 3-term split-bf16 ---
DEV void qk_mfma(const unsigned int* kh, const unsigned int* kl,
                 const s8_t* qh, const s8_t* ql, int lane, f4_t c[4]) {
  const int qi = lane & 15, g = lane >> 4;
#pragma unroll
  for (int t = 0; t < 4; ++t) {
    f4_t acc = {0.f, 0.f, 0.f, 0.f};
#pragma unroll
    for (int ks = 0; ks < 2; ++ks) {
      const int off = (t * 16 + qi) * 40 + ks * 16 + g * 4;
      const s8_t Bh = as_s8(*(const uint4*)(kh + off));
      const s8_t Bl = as_s8(*(const uint4*)(kl + off));
      acc = mfma16(qh[ks], Bh, acc);
      acc = mfma16(qh[ks], Bl, acc);
      acc = mfma16(ql[ks], Bh, acc);
    }
    c[t] = acc;
  }
}

// --- redistribute C frags (q-rows 0..7) -> per-lane raw[j] (lane = col) ---
DEV void redist(const f4_t c[4], float* scw /*[8][68]*/, int lane, float raw[8]) {
  if (lane < 32) {
    const int g2 = lane >> 4, ci = lane & 15;
#pragma unroll
    for (int t = 0; t < 4; ++t)
#pragma unroll
      for (int r = 0; r < 4; ++r)
        scw[(g2 * 4 + r) * 68 + t * 16 + ci] = c[t][r];
  }
  wave_fence();
#pragma unroll
  for (int j = 0; j < 8; ++j) raw[j] = scw[j * 68 + lane];
}

// ---------------------------------------------------------------------------
__global__ __launch_bounds__(64) void nsa_means(const float* __restrict__ k,
                                                const float* __restrict__ v,
                                                float* __restrict__ kblk,
                                                float* __restrict__ vblk) {
  const int n = blockIdx.x, bh = blockIdx.y, d = threadIdx.x;
  const float* kb = k + ((size_t)bh * SS + (size_t)n * BS) * DD;
  const float* vb = v + ((size_t)bh * SS + (size_t)n * BS) * DD;
  float sk = 0.f, sv = 0.f;
  for (int t = 0; t < BS; ++t) { sk += kb[t * DD + d]; sv += vb[t * DD + d]; }
  kblk[((size_t)bh * NBLK + n) * DD + d] = sk * (1.f / 64.f);
  vblk[((size_t)bh * NBLK + n) * DD + d] = sv * (1.f / 64.f);
}

// ---------------------------------------------------------------------------
__global__ __launch_bounds__(512) void nsa_main(
    const float* __restrict__ qg, const float* __restrict__ kg,
    const float* __restrict__ vg, const float* __restrict__ kblk,
    const float* __restrict__ vblk, float* __restrict__ outg) {
  const int qb   = blockIdx.x;
  const int bh   = blockIdx.y;
  const int tid  = threadIdx.x;
  const int w    = tid >> 6;
  const int lane = tid & 63;
  const int q0   = qb * BS;
  const size_t base = (size_t)bh * SS * DD;

  __shared__ __align__(16) unsigned int khl_s[2][64 * 40];  // 20480 B
  __shared__ __align__(16) float sc_f[8][8][68];            // 17408 B per-wave scratch
  __shared__ float kb_s[NBLK][65];                          // 8320
  __shared__ float vb_s[NBLK][65];                          // 8320
  __shared__ float logc_s[BS][NBLK];                        // 8192
  __shared__ float k0_s[DD], v0_s[DD];
  __shared__ float sc_s[NBLK];
  __shared__ int   sel_s[SNB];

  float* scw = &sc_f[w][0][0];
  unsigned short* scwu = (unsigned short*)scw;
  const int qi = lane & 15, g = lane >> 4;
  const int qc = (qi < 8) ? qi : 0;

  // ---- init: block means + global token + cmp-Q rows ----
  {
    const float* kb = kblk + (size_t)bh * NBLK * DD;
    const float* vb = vblk + (size_t)bh * NBLK * DD;
    for (int i = tid; i < NBLK * DD; i += 512) {
      kb_s[i >> 6][i & 63] = kb[i];
      vb_s[i >> 6][i & 63] = vb[i];
    }
    if (tid < DD) { k0_s[tid] = kg[base + tid]; v0_s[tid] = vg[base + tid]; }
  }
  {
    float qreg[8];
#pragma unroll
    for (int j = 0; j < 8; ++j)
      qreg[j] = qg[base + (size_t)(q0 + w * 8 + j) * DD + lane];
    __syncthreads();

    // ---- cmp QK: EXACT fp32 (selection-critical) ----
    const int n = lane & 31;
    float acc[8] = {0, 0, 0, 0, 0, 0, 0, 0};
#pragma unroll 4
    for (int d = 0; d < DD; ++d) {
      const float kd = kb_s[n][d];
#pragma unroll
      for (int j = 0; j < 8; ++j) acc[j] = fmaf(readlane_f(qreg[j], d), kd, acc[j]);
    }
    if (lane < 32) {
#pragma unroll
      for (int j = 0; j < 8; ++j) logc_s[w * 8 + j][n] = acc[j] * SCALE;
    }
  }

  // ---- build Q A-fragments (bf16 hi/lo) from global (L2-hot) ----
  s8_t qAh[2], qAl[2];
  {
    const float* qrow = qg + base + (size_t)(q0 + w * 8 + qc) * DD;
#pragma unroll
    for (int ks = 0; ks < 2; ++ks) {
      float f[8];
      const float4 a = *(const float4*)(qrow + ks * 32 + g * 8);
      const float4 b = *(const float4*)(qrow + ks * 32 + g * 8 + 4);
      f[0] = a.x; f[1] = a.y; f[2] = a.z; f[3] = a.w;
      f[4] = b.x; f[5] = b.y; f[6] = b.z; f[7] = b.w;
      S8H hh, ll;
#pragma unroll
      for (int e = 0; e < 8; ++e) {
        const float x = (qi < 8) ? f[e] : 0.f;
        hh.h[e] = f2bh(x);
        ll.h[e] = f2bh(x - bh2f(hh.h[e]));
      }
      qAh[ks] = hh.s; qAl[ks] = ll.s;
    }
  }
  __syncthreads();

  // ---- block scores ----
  if (tid < NBLK) {
    float s = NEGINF;
    if (tid <= qb) {
      float a = 0.f;
      for (int qq = 0; qq < BS; ++qq) a += logc_s[qq][tid];
      s = a * (1.f / 64.f);
    }
    sc_s[tid] = s;
  }
  __syncthreads();
  // ---- top-8: wave-parallel argmax, exact lax.top_k tie-break ----
  if (w == 0) {
    float s = (lane < NBLK) ? sc_s[lane] : -3.4e38f;
    const int bi = lane;
    for (int t = 0; t < SNB; ++t) {
      float bs = s; int bb = bi;
#pragma unroll
      for (int off = 32; off > 0; off >>= 1) {
        const float os = __shfl_xor(bs, off, 64);
        const int   ob = __shfl_xor(bb, off, 64);
        if (os > bs || (os == bs && ob < bb)) { bs = os; bb = ob; }
      }
      if (lane == 0) sel_s[t] = bb;
      if (bi == bb) s = -3.4e38f;
    }
  }
  __syncthreads();

  // ---- sel QK: 8 blocks, register-prefetched staging ----
  float L[8][SNB];
  float4 pfa, pfb;
  loadK(kg + base + (size_t)sel_s[0] * BS * DD, tid, pfa, pfb);
#pragma unroll
  for (int sbi = 0; sbi < SNB; ++sbi) {
    __syncthreads();                       // prior khl_s readers done
    writeK(khl_s[0], khl_s[1], pfa, pfb, tid);
    if (sbi < SNB - 1)
      loadK(kg + base + (size_t)sel_s[sbi + 1] * BS * DD, tid, pfa, pfb);
    __syncthreads();                       // khl_s ready
    f4_t c[4];
    qk_mfma(khl_s[0], khl_s[1], qAh, qAl, lane, c);
    float raw[8];
    redist(c, scw, lane, raw);
    const int tok = sel_s[sbi] * BS + lane;
#pragma unroll
    for (int j = 0; j < 8; ++j) {
      const int pos = q0 + w * 8 + j;
      L[j][sbi] = (tok <= pos) ? raw[j] * SCALE : NEGINF;
    }
  }

  // ---- threshold (float-window search) + sel softmax -> packed bf16 P ----
  unsigned Lp[8][4];
#pragma unroll
  for (int j = 0; j < 8; ++j) {
    float m = L[j][0];
#pragma unroll
    for (int i = 1; i < SNB; ++i) m = fmaxf(m, L[j][i]);
    m = wave_max(m);
    float lo = m - 20.f, hi = m;
    int c0 = 0;
#pragma unroll
    for (int i = 0; i < SNB; ++i) c0 += __popcll(__ballot(L[j][i] >= lo));
    if (c0 >= KKEEP) {
      for (int it = 0; it < 16; ++it) {
        const float mid = 0.5f * (lo + hi);
        int cc = 0;
#pragma unroll
        for (int i = 0; i < SNB; ++i) cc += __popcll(__ballot(L[j][i] >= mid));
        if (cc >= KKEEP) lo = mid; else hi = mid;
      }
    }
    const float thr = lo;
    float s = 0.f;
#pragma unroll
    for (int i = 0; i < SNB; ++i) {
      const float e = (L[j][i] >= thr) ? __expf(L[j][i] - m) : 0.f;
      L[j][i] = e; s += e;
    }
    s = wave_sum(s);
    const float inv = 1.f / s;
#pragma unroll
    for (int ip = 0; ip < 4; ++ip)
      Lp[j][ip] = (unsigned)f2bh(L[j][2 * ip] * inv) |
                  ((unsigned)f2bh(L[j][2 * ip + 1] * inv) << 16);
  }

  // ---- win QK: 3 blocks (clamped staging), prefetched ----
  float Lw[8][3];
  loadK(kg + base + (size_t)max(qb - 2, 0) * BS * DD, tid, pfa, pfb);
#pragma unroll
  for (int wi = 0; wi < 3; ++wi) {
    const int wb = qb - 2 + wi;
    __syncthreads();
    writeK(khl_s[0], khl_s[1], pfa, pfb, tid);
    if (wi < 2)
      loadK(kg + base + (size_t)max(qb - 1 + wi, 0) * BS * DD, tid, pfa, pfb);
    __syncthreads();
    f4_t c[4];
    qk_mfma(khl_s[0], khl_s[1], qAh, qAl, lane, c);
    float raw[8];
    redist(c, scw, lane, raw);
    const int tok = wb * BS + lane;
#pragma unroll
    for (int j = 0; j < 8; ++j) {
      const int pos = q0 + w * 8 + j;
      const bool valid = (wb >= 0) && (tok <= pos) && ((pos - tok < 128) || (tok == 0));
      Lw[j][wi] = valid ? raw[j] * SCALE : NEGINF;
    }
  }

  // ---- win softmax (+ exact global-token column when qb >= 3) ----
  unsigned Lwp[8][2];
  float p192[8];
#pragma unroll
  for (int j = 0; j < 8; ++j) {
    float l192 = NEGINF;
    if (qb >= 3) {
      const float qv = qg[base + (size_t)(q0 + w * 8 + j) * DD + lane];
      l192 = wave_sum(qv * k0_s[lane]) * SCALE;
    }
    float m = fmaxf(fmaxf(Lw[j][0], Lw[j][1]), Lw[j][2]);
    m = wave_max(m);
    m = fmaxf(m, l192);
    const float e0 = __expf(Lw[j][0] - m);
    const float e1 = __expf(Lw[j][1] - m);
    const float e2 = __expf(Lw[j][2] - m);
    float s = wave_sum(e0 + e1 + e2);
    const float e192 = (qb >= 3) ? __expf(l192 - m) : 0.f;
    s += e192;
    const float inv = 1.f / s;
    Lwp[j][0] = (unsigned)f2bh(e0 * inv) | ((unsigned)f2bh(e1 * inv) << 16);
    Lwp[j][1] = (unsigned)f2bh(e2 * inv);
    p192[j] = e192 * inv;
  }

  // ---- merged PV: 11 V blocks (8 sel + 3 win), prefetched, MFMA into Of ----
  f4_t Of[4];
#pragma unroll
  for (int t = 0; t < 4; ++t) Of[t] = (f4_t){0.f, 0.f, 0.f, 0.f};
  loadV(vg + base + (size_t)sel_s[0] * BS * DD, tid, pfa, pfb);
#pragma unroll
  for (int i = 0; i < 11; ++i) {
    __syncthreads();
    writeVT(khl_s[0], pfa, pfb, tid);
    if (i < 10) {
      const int nb = (i + 1 < 8) ? sel_s[i + 1] : max(qb - 9 + i, 0);
      loadV(vg + base + (size_t)nb * BS * DD, tid, pfa, pfb);
    }
    __syncthreads();
    // write this block's P column (bf16) to wave scratch, lane = token
#pragma unroll
    for (int j = 0; j < 8; ++j) {
      const unsigned uu = (i < 8) ? Lp[j][i >> 1] : Lwp[j][(i - 8) >> 1];
      const bool hiHalf = (i < 8) ? (i & 1) : ((i - 8) & 1);
      scwu[j * 136 + lane] = (unsigned short)(hiHalf ? (uu >> 16) : (uu & 0xffffu));
    }
    wave_fence();
#pragma unroll
    for (int ks = 0; ks < 2; ++ks) {
      s8_t Pa = as_s8(*(const uint4*)(scwu + qc * 136 + ks * 32 + g * 8));
      if (qi >= 8) Pa = (s8_t)0;
#pragma unroll
      for (int t = 0; t < 4; ++t) {
        const s8_t Vh = as_s8(*(const uint4*)(&khl_s[0][(t * 16 + qi) * 40 + ks * 16 + g * 4]));
        Of[t] = mfma16(Pa, Vh, Of[t]);
      }
    }
  }

  // ---- redistribute Of -> lane=dim ----
  float ofin[8];
  redist(Of, scw, lane, ofin);

  // ---- cmp softmax + PV (exact) ----
  float cmp_out[8];
  {
    const int n = lane & 31;
#pragma unroll
    for (int j = 0; j < 8; ++j) {
      const bool valid = (lane < 32) && (n <= qb);
      const float l = valid ? logc_s[w * 8 + j][n] : NEGINF;
      const float m = wave_max(l);
      const float e = valid ? __expf(l - m) : 0.f;
      const float ssum = wave_sum(e);
      const float p = e / ssum;
      float acc = 0.f;
      for (int n2 = 0; n2 <= qb; ++n2)
        acc = fmaf(readlane_f(p, n2), vb_s[n2][lane], acc);
      cmp_out[j] = acc;
    }
  }

  // ---- store (cmp + sel + win)/3 ----
#pragma unroll
  for (int j = 0; j < 8; ++j)
    outg[base + (size_t)(q0 + w * 8 + j) * DD + lane] =
        (ofin[j] + cmp_out[j] + fmaf(p192[j], v0_s[lane], 0.f)) * (1.f / 3.f);
}

// ---------------------------------------------------------------------------
extern "C" void kernel_launch(void* const* d_in, const int* in_sizes, int n_in,
                              void* d_out, int out_size, void* d_ws, size_t ws_size,
                              hipStream_t stream) {
  (void)in_sizes; (void)n_in; (void)out_size; (void)ws_size;
  const float* q = (const float*)d_in[0];
  const float* k = (const float*)d_in[1];
  const float* v = (const float*)d_in[2];
  float* out = (float*)d_out;
  float* wsf = (float*)d_ws;
  float* kblk = wsf;
  float* vblk = wsf + 16 * NBLK * DD;

  dim3 g1(NBLK, 16);
  nsa_means<<<g1, 64, 0, stream>>>(k, v, kblk, vblk);
  dim3 g2(NBLK, 16);
  nsa_main<<<g2, 512, 0, stream>>>(q, k, v, kblk, vblk, out);
}

// Round 5
// 128.347 us; speedup vs baseline: 1.1989x; 1.1989x over previous
//
#include <hip/hip_runtime.h>

// ---------------------------------------------------------------------------
// Native Sparse Attention (B=2, H=8, S=2048, D=64)
// Tile = (bh, qb): 64 queries. 512 threads = 8 waves, wave owns 8 queries.
// Block selection: exact fp32 via factorized scores (mean_q Q)·K̄ (wave 0).
// All three attention branches (cmp/sel/win): split-bf16 MFMA QK (3-term),
// bf16 MFMA PV. Staging uses raw s_barrier (lgkm-only fences) so register
// prefetch of the next block stays in flight across barriers (no vmcnt drain).
// ---------------------------------------------------------------------------

constexpr int SS   = 2048;
constexpr int DD   = 64;
constexpr int NBLK = 32;
constexpr int BS   = 64;
constexpr int SNB  = 8;
constexpr int KKEEP = 256;
constexpr float SCALE  = 0.125f;
constexpr float NEGINF = -1e30f;

#define DEV __device__ __forceinline__

typedef __attribute__((ext_vector_type(8))) short s8_t;   // 8 x bf16
typedef __attribute__((ext_vector_type(4))) float f4_t;   // MFMA C/D frag

union S8U { uint4 u; s8_t s; };
union S8H { unsigned short h[8]; s8_t s; };

DEV s8_t as_s8(uint4 u) { S8U x; x.u = u; return x.s; }

DEV float wave_max(float x) {
#pragma unroll
  for (int off = 32; off > 0; off >>= 1) x = fmaxf(x, __shfl_xor(x, off, 64));
  return x;
}
DEV float wave_sum(float x) {
#pragma unroll
  for (int off = 32; off > 0; off >>= 1) x += __shfl_xor(x, off, 64);
  return x;
}
DEV unsigned short f2bh(float x) {
  unsigned u = __float_as_uint(x);
  unsigned r = u + 0x7FFFu + ((u >> 16) & 1u);
  return (unsigned short)(r >> 16);
}
DEV float bh2f(unsigned short h) { return __uint_as_float(((unsigned)h) << 16); }

DEV f4_t mfma16(s8_t a, s8_t b, f4_t c) {
  return __builtin_amdgcn_mfma_f32_16x16x32_bf16(a, b, c, 0, 0, 0);
}
// wave-local LDS fence (own ds ops complete)
DEV void wave_fence() {
  asm volatile("s_waitcnt lgkmcnt(0)" ::: "memory");
  __builtin_amdgcn_sched_barrier(0);
}
// raw workgroup barrier with LDS-only fence: does NOT drain vmcnt, so
// in-flight global prefetch loads survive across it.
DEV void ldsbar() {
  asm volatile("s_waitcnt lgkmcnt(0)" ::: "memory");
  __builtin_amdgcn_sched_barrier(0);
  __builtin_amdgcn_s_barrier();
  __builtin_amdgcn_sched_barrier(0);
}

// ---- staging register loads (prefetchable) ----
DEV void loadK(const float* __restrict__ src, int tid, float4& a, float4& b) {
  const int r = tid >> 4, c4 = tid & 15;
  a = *(const float4*)(src + r * DD + c4 * 4);
  b = *(const float4*)(src + (r + 32) * DD + c4 * 4);
}
DEV void loadV(const float* __restrict__ src, int tid, float4& a, float4& b) {
  const int tp = tid & 31, dg = tid >> 5;
  a = *(const float4*)(src + (2 * tp) * DD + dg * 4);
  b = *(const float4*)(src + (2 * tp + 1) * DD + dg * 4);
}
// 32-row variant (block means): one float4 per thread
DEV void load32(const float* __restrict__ src, int tid, float4& a) {
  a = *(const float4*)(src + (tid >> 4) * DD + (tid & 15) * 4);
}

// convert + write K block split-bf16: [tok][dim-pairs], row stride 40 uints
DEV void writeK(unsigned int* kh, unsigned int* kl, const float4& a,
                const float4& b, int tid) {
  const int r = tid >> 4, c4 = tid & 15;
  const float fa[4] = {a.x, a.y, a.z, a.w};
  const float fb[4] = {b.x, b.y, b.z, b.w};
  unsigned short h[4], l[4];
#pragma unroll
  for (int i = 0; i < 4; ++i) { h[i] = f2bh(fa[i]); l[i] = f2bh(fa[i] - bh2f(h[i])); }
  kh[r * 40 + c4 * 2]     = (unsigned)h[0] | ((unsigned)h[1] << 16);
  kh[r * 40 + c4 * 2 + 1] = (unsigned)h[2] | ((unsigned)h[3] << 16);
  kl[r * 40 + c4 * 2]     = (unsigned)l[0] | ((unsigned)l[1] << 16);
  kl[r * 40 + c4 * 2 + 1] = (unsigned)l[2] | ((unsigned)l[3] << 16);
#pragma unroll
  for (int i = 0; i < 4; ++i) { h[i] = f2bh(fb[i]); l[i] = f2bh(fb[i] - bh2f(h[i])); }
  kh[(r + 32) * 40 + c4 * 2]     = (unsigned)h[0] | ((unsigned)h[1] << 16);
  kh[(r + 32) * 40 + c4 * 2 + 1] = (unsigned)h[2] | ((unsigned)h[3] << 16);
  kl[(r + 32) * 40 + c4 * 2]     = (unsigned)l[0] | ((unsigned)l[1] << 16);
  kl[(r + 32) * 40 + c4 * 2 + 1] = (unsigned)l[2] | ((unsigned)l[3] << 16);
}
// K-means stage: rows 0..31 real, rows 32..63 zeroed
DEV void writeKbar(unsigned int* kh, unsigned int* kl, const float4& a, int tid) {
  const int r = tid >> 4, c4 = tid & 15;
  const float fa[4] = {a.x, a.y, a.z, a.w};
  unsigned short h[4], l[4];
#pragma unroll
  for (int i = 0; i < 4; ++i) { h[i] = f2bh(fa[i]); l[i] = f2bh(fa[i] - bh2f(h[i])); }
  kh[r * 40 + c4 * 2]     = (unsigned)h[0] | ((unsigned)h[1] << 16);
  kh[r * 40 + c4 * 2 + 1] = (unsigned)h[2] | ((unsigned)h[3] << 16);
  kl[r * 40 + c4 * 2]     = (unsigned)l[0] | ((unsigned)l[1] << 16);
  kl[r * 40 + c4 * 2 + 1] = (unsigned)l[2] | ((unsigned)l[3] << 16);
  kh[(r + 32) * 40 + c4 * 2]     = 0; kh[(r + 32) * 40 + c4 * 2 + 1] = 0;
  kl[(r + 32) * 40 + c4 * 2]     = 0; kl[(r + 32) * 40 + c4 * 2 + 1] = 0;
}
// convert + write V transposed bf16-hi: [dim][tok-pairs], row stride 40 uints
DEV void writeVT(unsigned int* vh, const float4& a, const float4& b, int tid) {
  const int tp = tid & 31, dg = tid >> 5;
  const float fa[4] = {a.x, a.y, a.z, a.w};
  const float fb[4] = {b.x, b.y, b.z, b.w};
#pragma unroll
  for (int i = 0; i < 4; ++i)
    vh[(dg * 4 + i) * 40 + tp] = (unsigned)f2bh(fa[i]) | ((unsigned)f2bh(fb[i]) << 16);
}
// V-means stage: toks 0..31 (tp 0..15), tp 16..31 zeroed
DEV void writeVbarT(unsigned int* vh, const float4& a, int tid) {
  const int r = tid >> 4, c4 = tid & 15;
  const int tp = r >> 1, hf = r & 1;
  const float fa[4] = {a.x, a.y, a.z, a.w};
  unsigned short* vh16 = (unsigned short*)vh;
#pragma unroll
  for (int i = 0; i < 4; ++i)
    vh16[((c4 * 4 + i) * 40 + tp) * 2 + hf] = f2bh(fa[i]);
  vh[(tid >> 3) * 40 + 16 + (tid & 7) * 2]     = 0;
  vh[(tid >> 3) * 40 + 16 + (tid & 7) * 2 + 1] = 0;
}

// --- QK mfma: C[q][tok], K=64 dims, 3-term split-bf16 ---
DEV void qk_mfma(const unsigned int* kh, const unsigned int* kl,
                 const s8_t* qh, const s8_t* ql, int lane, f4_t c[4]) {
  const int qi = lane & 15, g = lane >> 4;
#pragma unroll
  for (int t = 0; t < 4; ++t) {
    f4_t acc = {0.f, 0.f, 0.f, 0.f};
#pragma unroll
    for (int ks = 0; ks < 2; ++ks) {
      const int off = (t * 16 + qi) * 40 + ks * 16 + g * 4;
      const s8_t Bh = as_s8(*(const uint4*)(kh + off));
      const s8_t Bl = as_s8(*(const uint4*)(kl + off));
      acc = mfma16(qh[ks], Bh, acc);
      acc = mfma16(qh[ks], Bl, acc);
      acc = mfma16(ql[ks], Bh, acc);
    }
    c[t] = acc;
  }
}

// --- redistribute C frags (q-rows 0..7) -> per-lane raw[j] (lane = col) ---
DEV void redist(const f4_t c[4], float* scw /*[8][68]*/, int lane, float raw[8]) {
  if (lane < 32) {
    const int g2 = lane >> 4, ci = lane & 15;
#pragma unroll
    for (int t = 0; t < 4; ++t)
#pragma unroll
      for (int r = 0; r < 4; ++r)
        scw[(g2 * 4 + r) * 68 + t * 16 + ci] = c[t][r];
  }
  wave_fence();
#pragma unroll
  for (int j = 0; j < 8; ++j) raw[j] = scw[j * 68 + lane];
}

// ---------------------------------------------------------------------------
__global__ __launch_bounds__(64) void nsa_means(const float* __restrict__ k,
                                                const float* __restrict__ v,
                                                float* __restrict__ kblk,
                                                float* __restrict__ vblk) {
  const int n = blockIdx.x, bh = blockIdx.y, d = threadIdx.x;
  const float* kb = k + ((size_t)bh * SS + (size_t)n * BS) * DD;
  const float* vb = v + ((size_t)bh * SS + (size_t)n * BS) * DD;
  float sk = 0.f, sv = 0.f;
  for (int t = 0; t < BS; ++t) { sk += kb[t * DD + d]; sv += vb[t * DD + d]; }
  kblk[((size_t)bh * NBLK + n) * DD + d] = sk * (1.f / 64.f);
  vblk[((size_t)bh * NBLK + n) * DD + d] = sv * (1.f / 64.f);
}

// ---------------------------------------------------------------------------
__global__ __launch_bounds__(512) void nsa_main(
    const float* __restrict__ qg, const float* __restrict__ kg,
    const float* __restrict__ vg, const float* __restrict__ kblk,
    const float* __restrict__ vblk, float* __restrict__ outg) {
  const int qb   = blockIdx.x;
  const int bh   = blockIdx.y;
  const int tid  = threadIdx.x;
  const int w    = tid >> 6;
  const int lane = tid & 63;
  const int q0   = qb * BS;
  const size_t base = (size_t)bh * SS * DD;

  __shared__ __align__(16) unsigned int khl_s[2][64 * 40];  // 20480 B
  __shared__ __align__(16) float sc_f[8][8][68];            // 17408 B per-wave scratch
  __shared__ float partial_s[8][64];                        // 2048 B
  __shared__ float qbar_s[64];
  __shared__ float k0_s[DD], v0_s[DD];
  __shared__ int   sel_s[SNB];

  float* scw = &sc_f[w][0][0];
  unsigned short* scwu = (unsigned short*)scw;
  const int qi = lane & 15, g = lane >> 4;
  const int qc = (qi < 8) ? qi : 0;
  const float* kbar = kblk + (size_t)bh * NBLK * DD;
  const float* vbar = vblk + (size_t)bh * NBLK * DD;

  // ---- init: Q-row partial sums (for exact block scores) + qA frags ----
  {
    float qs = 0.f;
#pragma unroll
    for (int j = 0; j < 8; ++j)
      qs += qg[base + (size_t)(q0 + w * 8 + j) * DD + lane];
    partial_s[w][lane] = qs;
    if (tid < DD) { k0_s[tid] = kg[base + tid]; v0_s[tid] = vg[base + tid]; }
  }
  s8_t qAh[2], qAl[2];
  {
    const float* qrow = qg + base + (size_t)(q0 + w * 8 + qc) * DD;
#pragma unroll
    for (int ks = 0; ks < 2; ++ks) {
      float f[8];
      const float4 a = *(const float4*)(qrow + ks * 32 + g * 8);
      const float4 b = *(const float4*)(qrow + ks * 32 + g * 8 + 4);
      f[0] = a.x; f[1] = a.y; f[2] = a.z; f[3] = a.w;
      f[4] = b.x; f[5] = b.y; f[6] = b.z; f[7] = b.w;
      S8H hh, ll;
#pragma unroll
      for (int e = 0; e < 8; ++e) {
        const float x = (qi < 8) ? f[e] : 0.f;
        hh.h[e] = f2bh(x);
        ll.h[e] = f2bh(x - bh2f(hh.h[e]));
      }
      qAh[ks] = hh.s; qAl[ks] = ll.s;
    }
  }
  // prefetch K-means stage
  float4 pfa, pfb;
  load32(kbar, tid, pfa);
  __syncthreads();

  // ---- exact block scores + top-8 (wave 0) ----
  if (w == 0) {
    float qm = 0.f;
#pragma unroll
    for (int ww = 0; ww < 8; ++ww) qm += partial_s[ww][lane];
    qbar_s[lane] = qm;   // unnormalized mean (positive scale: rank-invariant)
    wave_fence();
    const int n2 = lane & 31, half = lane >> 5;
    const float* krow = kbar + n2 * DD + half * 32;
    float p = 0.f;
#pragma unroll
    for (int dd = 0; dd < 32; ++dd) p = fmaf(qbar_s[half * 32 + dd], krow[dd], p);
    p += __shfl_xor(p, 32, 64);
    float s = (lane < 32) ? ((n2 <= qb) ? p : NEGINF) : -3.4e38f;
    const int bi = lane;
    for (int t = 0; t < SNB; ++t) {
      float bs = s; int bb = bi;
#pragma unroll
      for (int off = 32; off > 0; off >>= 1) {
        const float os = __shfl_xor(bs, off, 64);
        const int   ob = __shfl_xor(bb, off, 64);
        if (os > bs || (os == bs && ob < bb)) { bs = os; bb = ob; }
      }
      if (lane == 0) sel_s[t] = bb;
      if (bi == bb) s = -3.4e38f;
    }
  }

  // =================== K stages: K̄, sel x8, win x3 ===================
  unsigned cPp[4];
  // --- K̄ (cmp logits) ---
  ldsbar();                                   // (A) + publishes sel_s/qbar
  int selreg[SNB];
#pragma unroll
  for (int t = 0; t < SNB; ++t) selreg[t] = sel_s[t];
  writeKbar(khl_s[0], khl_s[1], pfa, tid);
  ldsbar();                                   // (B)
  loadK(kg + base + (size_t)selreg[0] * BS * DD, tid, pfa, pfb);
  {
    f4_t c[4];
    qk_mfma(khl_s[0], khl_s[1], qAh, qAl, lane, c);
    float raw[8];
    redist(c, scw, lane, raw);
    float cP[8];
#pragma unroll
    for (int j = 0; j < 8; ++j) {
      const bool valid = (lane < 32) && (lane <= qb);
      const float l = valid ? raw[j] * SCALE : NEGINF;
      const float m = wave_max(l);
      const float e = valid ? __expf(l - m) : 0.f;
      const float ssum = wave_sum(e);
      cP[j] = e / ssum;
    }
#pragma unroll
    for (int ip = 0; ip < 4; ++ip)
      cPp[ip] = (unsigned)f2bh(cP[2 * ip]) | ((unsigned)f2bh(cP[2 * ip + 1]) << 16);
  }

  // --- sel QK x8 ---
  float L[8][SNB];
#pragma unroll
  for (int sbi = 0; sbi < SNB; ++sbi) {
    ldsbar();
    writeK(khl_s[0], khl_s[1], pfa, pfb, tid);
    ldsbar();
    {
      const int nb = (sbi < SNB - 1) ? selreg[sbi + 1] : ((qb > 2) ? qb - 2 : 0);
      loadK(kg + base + (size_t)nb * BS * DD, tid, pfa, pfb);
    }
    f4_t c[4];
    qk_mfma(khl_s[0], khl_s[1], qAh, qAl, lane, c);
    float raw[8];
    redist(c, scw, lane, raw);
    const int tok = selreg[sbi] * BS + lane;
#pragma unroll
    for (int j = 0; j < 8; ++j) {
      const int pos = q0 + w * 8 + j;
      L[j][sbi] = (tok <= pos) ? raw[j] * SCALE : NEGINF;
    }
  }

  // ---- threshold (float-window search) + sel softmax -> packed bf16 ----
  unsigned Lp[8][4];
#pragma unroll
  for (int j = 0; j < 8; ++j) {
    float m = L[j][0];
#pragma unroll
    for (int i = 1; i < SNB; ++i) m = fmaxf(m, L[j][i]);
    m = wave_max(m);
    float lo = m - 20.f, hi = m;
    int c0 = 0;
#pragma unroll
    for (int i = 0; i < SNB; ++i) c0 += __popcll(__ballot(L[j][i] >= lo));
    if (c0 >= KKEEP) {
      for (int it = 0; it < 16; ++it) {
        const float mid = 0.5f * (lo + hi);
        int cc = 0;
#pragma unroll
        for (int i = 0; i < SNB; ++i) cc += __popcll(__ballot(L[j][i] >= mid));
        if (cc >= KKEEP) lo = mid; else hi = mid;
      }
    }
    const float thr = lo;
    float s = 0.f;
#pragma unroll
    for (int i = 0; i < SNB; ++i) {
      const float e = (L[j][i] >= thr) ? __expf(L[j][i] - m) : 0.f;
      L[j][i] = e; s += e;
    }
    s = wave_sum(s);
    const float inv = 1.f / s;
#pragma unroll
    for (int ip = 0; ip < 4; ++ip)
      Lp[j][ip] = (unsigned)f2bh(L[j][2 * ip] * inv) |
                  ((unsigned)f2bh(L[j][2 * ip + 1] * inv) << 16);
  }

  // --- win QK x3 ---
  float Lw[8][3];
#pragma unroll
  for (int wi = 0; wi < 3; ++wi) {
    const int wb = qb - 2 + wi;
    ldsbar();
    writeK(khl_s[0], khl_s[1], pfa, pfb, tid);
    ldsbar();
    if (wi < 2) {
      const int nb = (qb - 1 + wi > 0) ? qb - 1 + wi : 0;
      loadK(kg + base + (size_t)nb * BS * DD, tid, pfa, pfb);
    } else {
      load32(vbar, tid, pfa);   // prefetch V-means stage
    }
    f4_t c[4];
    qk_mfma(khl_s[0], khl_s[1], qAh, qAl, lane, c);
    float raw[8];
    redist(c, scw, lane, raw);
    const int tok = wb * BS + lane;
#pragma unroll
    for (int j = 0; j < 8; ++j) {
      const int pos = q0 + w * 8 + j;
      const bool valid = (wb >= 0) && (tok <= pos) && ((pos - tok < 128) || (tok == 0));
      Lw[j][wi] = valid ? raw[j] * SCALE : NEGINF;
    }
  }

  // ---- win softmax (+ exact global-token column when qb >= 3) ----
  unsigned Lwp[8][2];
  float p192[8];
#pragma unroll
  for (int j = 0; j < 8; ++j) {
    float l192 = NEGINF;
    if (qb >= 3) {
      const float qv = qg[base + (size_t)(q0 + w * 8 + j) * DD + lane];
      l192 = wave_sum(qv * k0_s[lane]) * SCALE;
    }
    float m = fmaxf(fmaxf(Lw[j][0], Lw[j][1]), Lw[j][2]);
    m = wave_max(m);
    m = fmaxf(m, l192);
    const float e0 = __expf(Lw[j][0] - m);
    const float e1 = __expf(Lw[j][1] - m);
    const float e2 = __expf(Lw[j][2] - m);
    float s = wave_sum(e0 + e1 + e2);
    const float e192 = (qb >= 3) ? __expf(l192 - m) : 0.f;
    s += e192;
    const float inv = 1.f / s;
    Lwp[j][0] = (unsigned)f2bh(e0 * inv) | ((unsigned)f2bh(e1 * inv) << 16);
    Lwp[j][1] = (unsigned)f2bh(e2 * inv);
    p192[j] = e192 * inv;
  }

  // =================== V stages: V̄, sel x8, win x3 ===================
  f4_t Of[4];
#pragma unroll
  for (int t = 0; t < 4; ++t) Of[t] = (f4_t){0.f, 0.f, 0.f, 0.f};

  // --- V̄ (cmp PV) ---
  ldsbar();
  writeVbarT(khl_s[0], pfa, tid);
  ldsbar();
  loadV(vg + base + (size_t)selreg[0] * BS * DD, tid, pfa, pfb);
  {
#pragma unroll
    for (int j = 0; j < 8; ++j) {
      const unsigned uu = cPp[j >> 1];
      const unsigned short pv = (unsigned short)((j & 1) ? (uu >> 16) : (uu & 0xffffu));
      scwu[j * 136 + lane] = (lane < 32) ? pv : (unsigned short)0;
    }
    wave_fence();
#pragma unroll
    for (int ks = 0; ks < 2; ++ks) {
      s8_t Pa = as_s8(*(const uint4*)(scwu + qc * 136 + ks * 32 + g * 8));
      if (qi >= 8) Pa = (s8_t)0;
#pragma unroll
      for (int t = 0; t < 4; ++t) {
        const s8_t Vh = as_s8(*(const uint4*)(&khl_s[0][(t * 16 + qi) * 40 + ks * 16 + g * 4]));
        Of[t] = mfma16(Pa, Vh, Of[t]);
      }
    }
  }
  // --- sel PV x8 ---
#pragma unroll
  for (int sbi = 0; sbi < SNB; ++sbi) {
    ldsbar();
    writeVT(khl_s[0], pfa, pfb, tid);
    ldsbar();
    {
      const int nb = (sbi < SNB - 1) ? selreg[sbi + 1] : ((qb > 2) ? qb - 2 : 0);
      loadV(vg + base + (size_t)nb * BS * DD, tid, pfa, pfb);
    }
#pragma unroll
    for (int j = 0; j < 8; ++j) {
      const unsigned uu = Lp[j][sbi >> 1];
      scwu[j * 136 + lane] = (unsigned short)((sbi & 1) ? (uu >> 16) : (uu & 0xffffu));
    }
    wave_fence();
#pragma unroll
    for (int ks = 0; ks < 2; ++ks) {
      s8_t Pa = as_s8(*(const uint4*)(scwu + qc * 136 + ks * 32 + g * 8));
      if (qi >= 8) Pa = (s8_t)0;
#pragma unroll
      for (int t = 0; t < 4; ++t) {
        const s8_t Vh = as_s8(*(const uint4*)(&khl_s[0][(t * 16 + qi) * 40 + ks * 16 + g * 4]));
        Of[t] = mfma16(Pa, Vh, Of[t]);
      }
    }
  }
  // --- win PV x3 ---
#pragma unroll
  for (int wi = 0; wi < 3; ++wi) {
    ldsbar();
    writeVT(khl_s[0], pfa, pfb, tid);
    ldsbar();
    if (wi < 2) {
      const int nb = (qb - 1 + wi > 0) ? qb - 1 + wi : 0;
      loadV(vg + base + (size_t)nb * BS * DD, tid, pfa, pfb);
    }
#pragma unroll
    for (int j = 0; j < 8; ++j) {
      const unsigned uu = Lwp[j][wi >> 1];
      scwu[j * 136 + lane] = (unsigned short)((wi & 1) ? (uu >> 16) : (uu & 0xffffu));
    }
    wave_fence();
#pragma unroll
    for (int ks = 0; ks < 2; ++ks) {
      s8_t Pa = as_s8(*(const uint4*)(scwu + qc * 136 + ks * 32 + g * 8));
      if (qi >= 8) Pa = (s8_t)0;
#pragma unroll
      for (int t = 0; t < 4; ++t) {
        const s8_t Vh = as_s8(*(const uint4*)(&khl_s[0][(t * 16 + qi) * 40 + ks * 16 + g * 4]));
        Of[t] = mfma16(Pa, Vh, Of[t]);
      }
    }
  }

  // ---- epilogue: redistribute Of -> lane=dim; add global-token term ----
  float ofin[8];
  redist(Of, scw, lane, ofin);
#pragma unroll
  for (int j = 0; j < 8; ++j)
    outg[base + (size_t)(q0 + w * 8 + j) * DD + lane] =
        (ofin[j] + p192[j] * v0_s[lane]) * (1.f / 3.f);
}

// ---------------------------------------------------------------------------
extern "C" void kernel_launch(void* const* d_in, const int* in_sizes, int n_in,
                              void* d_out, int out_size, void* d_ws, size_t ws_size,
                              hipStream_t stream) {
  (void)in_sizes; (void)n_in; (void)out_size; (void)ws_size;
  const float* q = (const float*)d_in[0];
  const float* k = (const float*)d_in[1];
  const float* v = (const float*)d_in[2];
  float* out = (float*)d_out;
  float* wsf = (float*)d_ws;
  float* kblk = wsf;
  float* vblk = wsf + 16 * NBLK * DD;

  dim3 g1(NBLK, 16);
  nsa_means<<<g1, 64, 0, stream>>>(k, v, kblk, vblk);
  dim3 g2(NBLK, 16);
  nsa_main<<<g2, 512, 0, stream>>>(q, k, v, kblk, vblk, out);
}

// Round 6
// 108.501 us; speedup vs baseline: 1.4183x; 1.1829x over previous
//
#include <hip/hip_runtime.h>

// ---------------------------------------------------------------------------
// Native Sparse Attention (B=2, H=8, S=2048, D=64)
// Tile = (bh, qb): 64 queries. 512 threads = 8 waves, wave owns 8 queries.
// Block top-8: exact fp32 factorized (mean_q Q)·K̄, computed redundantly
// per-wave. All attention branches: bf16 MFMA QK + bf16 MFMA PV.
// Global token folded into means stages (k0 -> K̄ row 32, v0 -> V̄ tok 32).
// Double-buffered LDS staging, ONE raw s_barrier (lgkm-only) per stage;
// next-stage global loads stay in flight across the barrier.
// ---------------------------------------------------------------------------

constexpr int SS   = 2048;
constexpr int DD   = 64;
constexpr int NBLK = 32;
constexpr int BS   = 64;
constexpr int SNB  = 8;
constexpr int KKEEP = 256;
constexpr float SCALE  = 0.125f;
constexpr float NEGINF = -1e30f;

#define DEV __device__ __forceinline__

typedef __attribute__((ext_vector_type(8))) short s8_t;   // 8 x bf16
typedef __attribute__((ext_vector_type(4))) float f4_t;   // MFMA C/D frag

union S8U { uint4 u; s8_t s; };

DEV s8_t as_s8(uint4 u) { S8U x; x.u = u; return x.s; }
DEV s8_t s8zero() { uint4 z = {0, 0, 0, 0}; return as_s8(z); }

DEV float readlane_f(float x, int l) {
  return __int_as_float(__builtin_amdgcn_readlane(__float_as_int(x), l));
}
DEV float wave_max(float x) {
#pragma unroll
  for (int o = 32; o > 0; o >>= 1) x = fmaxf(x, __shfl_xor(x, o, 64));
  return x;
}
DEV float wave_sum(float x) {
#pragma unroll
  for (int o = 32; o > 0; o >>= 1) x += __shfl_xor(x, o, 64);
  return x;
}
// HW packed f32->bf16 (RNE): dst = bf16(lo) | bf16(hi)<<16
DEV unsigned cvt_pk(float lo, float hi) {
  unsigned d;
  asm("v_cvt_pk_bf16_f32 %0, %1, %2" : "=v"(d) : "v"(lo), "v"(hi));
  return d;
}
DEV f4_t mfma16(s8_t a, s8_t b, f4_t c) {
  return __builtin_amdgcn_mfma_f32_16x16x32_bf16(a, b, c, 0, 0, 0);
}
DEV void wave_fence() {
  asm volatile("s_waitcnt lgkmcnt(0)" ::: "memory");
  __builtin_amdgcn_sched_barrier(0);
}
// raw workgroup barrier, LDS-only fence: vmcnt NOT drained.
DEV void ldsbar() {
  asm volatile("s_waitcnt lgkmcnt(0)" ::: "memory");
  __builtin_amdgcn_sched_barrier(0);
  __builtin_amdgcn_s_barrier();
  __builtin_amdgcn_sched_barrier(0);
}

// ---- staging loads (prefetchable). 512 threads. ----
DEV void loadK(const float* __restrict__ src, int tid, float4& a, float4& b) {
  const int r = tid >> 4, c4 = tid & 15;
  a = *(const float4*)(src + r * DD + c4 * 4);
  b = *(const float4*)(src + (r + 32) * DD + c4 * 4);
}
DEV void loadV(const float* __restrict__ src, int tid, float4& a, float4& b) {
  const int tp = tid & 31, dg = tid >> 5;
  a = *(const float4*)(src + (2 * tp) * DD + dg * 4);
  b = *(const float4*)(src + (2 * tp + 1) * DD + dg * 4);
}

// K-stage write: [tok 64][dim 64] bf16, row stride 36 uints (72 shorts)
DEV void writeKs(unsigned* b, const float4& a, const float4& bb, int tid) {
  const int r = tid >> 4, c4 = tid & 15;
  b[r * 36 + c4 * 2]     = cvt_pk(a.x, a.y);
  b[r * 36 + c4 * 2 + 1] = cvt_pk(a.z, a.w);
  b[(r + 32) * 36 + c4 * 2]     = cvt_pk(bb.x, bb.y);
  b[(r + 32) * 36 + c4 * 2 + 1] = cvt_pk(bb.z, bb.w);
}
// K̄ stage: rows 0..31 = block means, row 32 = k0, rows 33..63 = 0
DEV void writeKbar(unsigned* b, const float4& a, const float4& k0v, int tid) {
  const int r = tid >> 4, c4 = tid & 15;
  b[r * 36 + c4 * 2]     = cvt_pk(a.x, a.y);
  b[r * 36 + c4 * 2 + 1] = cvt_pk(a.z, a.w);
  const unsigned u0 = (r == 0) ? cvt_pk(k0v.x, k0v.y) : 0u;
  const unsigned u1 = (r == 0) ? cvt_pk(k0v.z, k0v.w) : 0u;
  b[(r + 32) * 36 + c4 * 2]     = u0;
  b[(r + 32) * 36 + c4 * 2 + 1] = u1;
}
// V-stage write (transposed): [dim 64][tok 64] bf16, row stride 36 uints
DEV void writeVT(unsigned* b, const float4& a, const float4& bb, int tid) {
  const int tp = tid & 31, dg = tid >> 5;
  const float fa[4] = {a.x, a.y, a.z, a.w};
  const float fb[4] = {bb.x, bb.y, bb.z, bb.w};
#pragma unroll
  for (int i = 0; i < 4; ++i)
    b[(dg * 4 + i) * 36 + tp] = cvt_pk(fa[i], fb[i]);
}
// V̄ stage: toks 0..31 = means, tok 32 = v0, rest 0
DEV void writeVbar(unsigned* b, const float4& a, const float4& bb,
                   const float4& v0f, int tid) {
  const int tp = tid & 31, dg = tid >> 5;
  const float fa[4] = {a.x, a.y, a.z, a.w};
  const float fb[4] = {bb.x, bb.y, bb.z, bb.w};
  const float f0[4] = {v0f.x, v0f.y, v0f.z, v0f.w};
#pragma unroll
  for (int i = 0; i < 4; ++i) {
    unsigned val = (tp < 16) ? cvt_pk(fa[i], fb[i])
                             : ((tp == 16) ? cvt_pk(f0[i], 0.f) : 0u);
    b[(dg * 4 + i) * 36 + tp] = val;
  }
}

// QK: 8 MFMA, B-frags from K buffer (row = token)
DEV void qk8(const unsigned* b, const s8_t qA[2], int qi, int g, f4_t c[4]) {
#pragma unroll
  for (int t = 0; t < 4; ++t) {
    f4_t acc = {0.f, 0.f, 0.f, 0.f};
#pragma unroll
    for (int ks = 0; ks < 2; ++ks) {
      const s8_t B = as_s8(*(const uint4*)(b + (t * 16 + qi) * 36 + ks * 16 + g * 4));
      acc = mfma16(qA[ks], B, acc);
    }
    c[t] = acc;
  }
}

// redistribute C frags (q-rows 0..7) -> per-lane raw[j] (lane = col)
DEV void redist(const f4_t c[4], float* scw, int lane, float raw[8]) {
  if (lane < 32) {
    const int g2 = lane >> 4, ci = lane & 15;
#pragma unroll
    for (int t = 0; t < 4; ++t)
#pragma unroll
      for (int r = 0; r < 4; ++r)
        scw[(g2 * 4 + r) * 68 + t * 16 + ci] = c[t][r];
  }
  wave_fence();
#pragma unroll
  for (int j = 0; j < 8; ++j) raw[j] = scw[j * 68 + lane];
}

// ---------------------------------------------------------------------------
__global__ __launch_bounds__(64) void nsa_means(const float* __restrict__ k,
                                                const float* __restrict__ v,
                                                float* __restrict__ kblk,
                                                float* __restrict__ vblk) {
  const int n = blockIdx.x, bh = blockIdx.y, d = threadIdx.x;
  const float* kb = k + ((size_t)bh * SS + (size_t)n * BS) * DD;
  const float* vb = v + ((size_t)bh * SS + (size_t)n * BS) * DD;
  float sk = 0.f, sv = 0.f;
  for (int t = 0; t < BS; ++t) { sk += kb[t * DD + d]; sv += vb[t * DD + d]; }
  kblk[((size_t)bh * NBLK + n) * DD + d] = sk * (1.f / 64.f);
  vblk[((size_t)bh * NBLK + n) * DD + d] = sv * (1.f / 64.f);
}

// ---------------------------------------------------------------------------
__global__ __launch_bounds__(512) void nsa_main(
    const float* __restrict__ qg, const float* __restrict__ kg,
    const float* __restrict__ vg, const float* __restrict__ kblk,
    const float* __restrict__ vblk, float* __restrict__ outg) {
  const int qb   = blockIdx.x;
  const int bh   = blockIdx.y;
  const int tid  = threadIdx.x;
  const int w    = tid >> 6;
  const int lane = tid & 63;
  const int q0   = qb * BS;
  const size_t base = (size_t)bh * SS * DD;

  __shared__ __align__(16) unsigned buf_s[2][64 * 36];   // 18432 B
  __shared__ __align__(16) float sc_f[8][8][68];         // 17408 B per-wave
  __shared__ float partial_s[8][64];                     // 2048 B

  float* scw = &sc_f[w][0][0];
  unsigned short* scwu = (unsigned short*)scw;
  const int qi = lane & 15, g = lane >> 4;
  const int qc = (qi < 8) ? qi : 0;
  const float* kbar = kblk + (size_t)bh * NBLK * DD;
  const float* vbar = vblk + (size_t)bh * NBLK * DD;

  // ---- prologue: partial Q sums, qA frags, stage-0 loads ----
  {
    float qs = 0.f;
#pragma unroll
    for (int j = 0; j < 8; ++j)
      qs += qg[base + (size_t)(q0 + w * 8 + j) * DD + lane];
    partial_s[w][lane] = qs;
  }
  s8_t qA[2];
  {
    const float* qrow = qg + base + (size_t)(q0 + w * 8 + qc) * DD;
#pragma unroll
    for (int ks = 0; ks < 2; ++ks) {
      const float4 a = *(const float4*)(qrow + ks * 32 + g * 8);
      const float4 b = *(const float4*)(qrow + ks * 32 + g * 8 + 4);
      uint4 uu = {cvt_pk(a.x, a.y), cvt_pk(a.z, a.w),
                  cvt_pk(b.x, b.y), cvt_pk(b.z, b.w)};
      qA[ks] = (qi < 8) ? as_s8(uu) : s8zero();
    }
  }
  float4 pfa, pfb, pfx;  // staging prefetch regs
  {
    const int r = tid >> 4, c4 = tid & 15;
    pfa = *(const float4*)(kbar + r * DD + c4 * 4);          // K̄ rows
    pfx = *(const float4*)(kg + base + c4 * 4);              // k0
  }
  ldsbar();   // publish partial_s (global loads survive)

  // ---- per-wave redundant exact block scores + top-8 ----
  int selreg[SNB];
  {
    float qm = 0.f;
#pragma unroll
    for (int ww = 0; ww < 8; ++ww) qm += partial_s[ww][lane];
    scw[lane] = qm;
    wave_fence();
    const int n2 = lane & 31, half = lane >> 5;
    const float* krow = kbar + n2 * DD + half * 32;
    float p = 0.f;
#pragma unroll
    for (int dd = 0; dd < 32; ++dd) p = fmaf(scw[half * 32 + dd], krow[dd], p);
    p += __shfl_xor(p, 32, 64);
    float s = (lane < 32) ? ((n2 <= qb) ? p : NEGINF) : -3.4e38f;
    const int bi = lane;
    for (int t = 0; t < SNB; ++t) {
      float bs = s; int bb = bi;
#pragma unroll
      for (int o = 32; o > 0; o >>= 1) {
        const float os = __shfl_xor(bs, o, 64);
        const int   ob = __shfl_xor(bb, o, 64);
        if (os > bs || (os == bs && ob < bb)) { bs = os; bb = ob; }
      }
      selreg[t] = bb;
      if (bi == bb) s = -3.4e38f;
    }
  }

  // =================== K phase: stage 0 = K̄(+k0), 1..8 sel, 9..11 win ======
  float cPp4[4];   // cmp probs packed (as float-bits storage of uints)
  unsigned cPp[4];
  float l192[8];
  // --- stage 0 ---
  writeKbar(buf_s[0], pfa, pfx, tid);
  loadK(kg + base + (size_t)selreg[0] * BS * DD, tid, pfa, pfb);
  ldsbar();
  {
    f4_t c[4];
    qk8(buf_s[0], qA, qi, g, c);
    float raw[8];
    redist(c, scw, lane, raw);
    float cPf[8];
#pragma unroll
    for (int j = 0; j < 8; ++j) {
      l192[j] = readlane_f(raw[j], 32) * SCALE;
      const bool valid = (lane < 32) && (lane <= qb);
      const float l = valid ? raw[j] * SCALE : NEGINF;
      const float m = wave_max(l);
      const float e = valid ? __expf(l - m) : 0.f;
      const float ssum = wave_sum(e);
      cPf[j] = e / ssum;
    }
#pragma unroll
    for (int ip = 0; ip < 4; ++ip) cPp[ip] = cvt_pk(cPf[2 * ip], cPf[2 * ip + 1]);
  }
  (void)cPp4;

  // --- stages 1..8: sel QK ---
  float L[8][SNB];
#pragma unroll
  for (int sbi = 0; sbi < SNB; ++sbi) {
    unsigned* buf = buf_s[(1 + sbi) & 1];
    writeKs(buf, pfa, pfb, tid);
    {
      const int nb = (sbi < SNB - 1) ? selreg[sbi + 1] : ((qb > 2) ? qb - 2 : 0);
      loadK(kg + base + (size_t)nb * BS * DD, tid, pfa, pfb);
    }
    ldsbar();
    f4_t c[4];
    qk8(buf, qA, qi, g, c);
    float raw[8];
    redist(c, scw, lane, raw);
    const int tok = selreg[sbi] * BS + lane;
#pragma unroll
    for (int j = 0; j < 8; ++j) {
      const int pos = q0 + w * 8 + j;
      L[j][sbi] = (tok <= pos) ? raw[j] * SCALE : NEGINF;
    }
  }

  // ---- threshold (float-window) + sel softmax -> packed bf16 ----
  unsigned Lp[8][4];
#pragma unroll
  for (int j = 0; j < 8; ++j) {
    float m = L[j][0];
#pragma unroll
    for (int i = 1; i < SNB; ++i) m = fmaxf(m, L[j][i]);
    m = wave_max(m);
    float lo = m - 20.f, hi = m;
    int c0 = 0;
#pragma unroll
    for (int i = 0; i < SNB; ++i) c0 += __popcll(__ballot(L[j][i] >= lo));
    if (c0 >= KKEEP) {
      for (int it = 0; it < 16; ++it) {
        const float mid = 0.5f * (lo + hi);
        int cc = 0;
#pragma unroll
        for (int i = 0; i < SNB; ++i) cc += __popcll(__ballot(L[j][i] >= mid));
        if (cc >= KKEEP) lo = mid; else hi = mid;
      }
    }
    const float thr = lo;
    float s = 0.f;
#pragma unroll
    for (int i = 0; i < SNB; ++i) {
      const float e = (L[j][i] >= thr) ? __expf(L[j][i] - m) : 0.f;
      L[j][i] = e; s += e;
    }
    s = wave_sum(s);
    const float inv = 1.f / s;
#pragma unroll
    for (int ip = 0; ip < 4; ++ip)
      Lp[j][ip] = cvt_pk(L[j][2 * ip] * inv, L[j][2 * ip + 1] * inv);
  }

  // --- stages 9..11: win QK ---
  float Lw[8][3];
#pragma unroll
  for (int wi = 0; wi < 3; ++wi) {
    const int wb = qb - 2 + wi;
    unsigned* buf = buf_s[(9 + wi) & 1];
    writeKs(buf, pfa, pfb, tid);
    if (wi < 2) {
      const int nb = (qb - 1 + wi > 0) ? qb - 1 + wi : 0;
      loadK(kg + base + (size_t)nb * BS * DD, tid, pfa, pfb);
    } else {
      // prefetch V̄ stage
      const int tp = tid & 31, dg = tid >> 5;
      if (tp < 16) {
        pfa = *(const float4*)(vbar + (2 * tp) * DD + dg * 4);
        pfb = *(const float4*)(vbar + (2 * tp + 1) * DD + dg * 4);
      }
      pfx = *(const float4*)(vg + base + dg * 4);   // v0
    }
    ldsbar();
    f4_t c[4];
    qk8(buf, qA, qi, g, c);
    float raw[8];
    redist(c, scw, lane, raw);
    const int tok = wb * BS + lane;
#pragma unroll
    for (int j = 0; j < 8; ++j) {
      const int pos = q0 + w * 8 + j;
      const bool valid = (wb >= 0) && (tok <= pos) && ((pos - tok < 128) || (tok == 0));
      Lw[j][wi] = valid ? raw[j] * SCALE : NEGINF;
    }
  }

  // ---- win softmax (l192 from K̄ stage column 32) ----
  unsigned Lwp[8][2];
  float p192[8];
#pragma unroll
  for (int j = 0; j < 8; ++j) {
    const float l1 = (qb >= 3) ? l192[j] : NEGINF;
    float m = fmaxf(fmaxf(Lw[j][0], Lw[j][1]), Lw[j][2]);
    m = wave_max(m);
    m = fmaxf(m, l1);
    const float e0 = __expf(Lw[j][0] - m);
    const float e1 = __expf(Lw[j][1] - m);
    const float e2 = __expf(Lw[j][2] - m);
    float s = wave_sum(e0 + e1 + e2);
    const float e192 = (qb >= 3) ? __expf(l1 - m) : 0.f;
    s += e192;
    const float inv = 1.f / s;
    Lwp[j][0] = cvt_pk(e0 * inv, e1 * inv);
    Lwp[j][1] = cvt_pk(e2 * inv, 0.f);
    p192[j] = e192 * inv;
  }

  // =================== V phase: stage 12 = V̄(+v0), 13..20 sel, 21..23 win ==
  f4_t Of[4];
#pragma unroll
  for (int t = 0; t < 4; ++t) Of[t] = (f4_t){0.f, 0.f, 0.f, 0.f};

  // --- stage 12: V̄ ---
  writeVbar(buf_s[0], pfa, pfb, pfx, tid);
  {
    // P row: lanes 0..31 cmp probs, lane 32 = p192, rest 0
#pragma unroll
    for (int j = 0; j < 8; ++j) {
      const unsigned uu = cPp[j >> 1];
      unsigned short pv = (unsigned short)((j & 1) ? (uu >> 16) : (uu & 0xffffu));
      if (lane == 32) pv = (unsigned short)(cvt_pk(p192[j], 0.f) & 0xffffu);
      else if (lane > 32) pv = 0;
      scwu[j * 136 + lane] = pv;
    }
  }
  loadV(vg + base + (size_t)selreg[0] * BS * DD, tid, pfa, pfb);
  ldsbar();
#pragma unroll
  for (int ks = 0; ks < 2; ++ks) {
    s8_t Pa = as_s8(*(const uint4*)(scwu + qc * 136 + ks * 32 + g * 8));
    if (qi >= 8) Pa = s8zero();
#pragma unroll
    for (int t = 0; t < 4; ++t) {
      const s8_t Vt = as_s8(*(const uint4*)(buf_s[0] + (t * 16 + qi) * 36 + ks * 16 + g * 4));
      Of[t] = mfma16(Pa, Vt, Of[t]);
    }
  }

  // --- stages 13..20: sel PV ---
#pragma unroll
  for (int sbi = 0; sbi < SNB; ++sbi) {
    unsigned* buf = buf_s[(13 + sbi) & 1];
    writeVT(buf, pfa, pfb, tid);
#pragma unroll
    for (int j = 0; j < 8; ++j) {
      const unsigned uu = Lp[j][sbi >> 1];
      scwu[j * 136 + lane] = (unsigned short)((sbi & 1) ? (uu >> 16) : (uu & 0xffffu));
    }
    {
      const int nb = (sbi < SNB - 1) ? selreg[sbi + 1] : ((qb > 2) ? qb - 2 : 0);
      loadV(vg + base + (size_t)nb * BS * DD, tid, pfa, pfb);
    }
    ldsbar();
#pragma unroll
    for (int ks = 0; ks < 2; ++ks) {
      s8_t Pa = as_s8(*(const uint4*)(scwu + qc * 136 + ks * 32 + g * 8));
      if (qi >= 8) Pa = s8zero();
#pragma unroll
      for (int t = 0; t < 4; ++t) {
        const s8_t Vt = as_s8(*(const uint4*)(buf + (t * 16 + qi) * 36 + ks * 16 + g * 4));
        Of[t] = mfma16(Pa, Vt, Of[t]);
      }
    }
  }

  // --- stages 21..23: win PV ---
#pragma unroll
  for (int wi = 0; wi < 3; ++wi) {
    unsigned* buf = buf_s[(21 + wi) & 1];
    writeVT(buf, pfa, pfb, tid);
#pragma unroll
    for (int j = 0; j < 8; ++j) {
      const unsigned uu = Lwp[j][wi >> 1];
      scwu[j * 136 + lane] = (unsigned short)((wi & 1) ? (uu >> 16) : (uu & 0xffffu));
    }
    if (wi < 2) {
      const int nb = (qb - 1 + wi > 0) ? qb - 1 + wi : 0;
      loadV(vg + base + (size_t)nb * BS * DD, tid, pfa, pfb);
    }
    ldsbar();
#pragma unroll
    for (int ks = 0; ks < 2; ++ks) {
      s8_t Pa = as_s8(*(const uint4*)(scwu + qc * 136 + ks * 32 + g * 8));
      if (qi >= 8) Pa = s8zero();
#pragma unroll
      for (int t = 0; t < 4; ++t) {
        const s8_t Vt = as_s8(*(const uint4*)(buf + (t * 16 + qi) * 36 + ks * 16 + g * 4));
        Of[t] = mfma16(Pa, Vt, Of[t]);
      }
    }
  }

  // ---- epilogue: Of -> lane=dim, store /3 (cmp+sel+win+global all inside) --
  float ofin[8];
  redist(Of, scw, lane, ofin);
#pragma unroll
  for (int j = 0; j < 8; ++j)
    outg[base + (size_t)(q0 + w * 8 + j) * DD + lane] = ofin[j] * (1.f / 3.f);
}

// ---------------------------------------------------------------------------
extern "C" void kernel_launch(void* const* d_in, const int* in_sizes, int n_in,
                              void* d_out, int out_size, void* d_ws, size_t ws_size,
                              hipStream_t stream) {
  (void)in_sizes; (void)n_in; (void)out_size; (void)ws_size;
  const float* q = (const float*)d_in[0];
  const float* k = (const float*)d_in[1];
  const float* v = (const float*)d_in[2];
  float* out = (float*)d_out;
  float* wsf = (float*)d_ws;
  float* kblk = wsf;
  float* vblk = wsf + 16 * NBLK * DD;

  dim3 g1(NBLK, 16);
  nsa_means<<<g1, 64, 0, stream>>>(k, v, kblk, vblk);
  dim3 g2(NBLK, 16);
  nsa_main<<<g2, 512, 0, stream>>>(q, k, v, kblk, vblk, out);
}